// Round 8
// baseline (288.459 us; speedup 1.0000x reference)
//
#include <hip/hip_runtime.h>

#define NN 10000      // nodes
#define NNPAD 10112   // padded: 158*64 = 79*128
#define NE 160000     // edges
#define HF 512        // hidden/in features
#define LL 6          // layers
#define NC 64         // classes
#define KCAT (LL*HF)  // 3072
#define BN_EPS 1e-5f

typedef _Float16 f16x8 __attribute__((ext_vector_type(8)));
typedef _Float16 f16x4 __attribute__((ext_vector_type(4)));
typedef float f32x4 __attribute__((ext_vector_type(4)));

#define GLB(p) ((const __attribute__((address_space(1))) void*)(p))
#define LDSP(p) ((__attribute__((address_space(3))) void*)(p))

// ---------------- setup kernels ----------------

__global__ void zero_u32_kernel(unsigned* __restrict__ p, int n) {
  int i = blockIdx.x * blockDim.x + threadIdx.x;
  if (i < n) p[i] = 0u;
}

__global__ void deg_kernel(const int* __restrict__ src, const int* __restrict__ dst,
                           unsigned* __restrict__ cnt_out, unsigned* __restrict__ cnt_in) {
  int e = blockIdx.x * blockDim.x + threadIdx.x;
  if (e < NE) {
    atomicAdd(&cnt_out[src[e]], 1u);
    atomicAdd(&cnt_in[dst[e]], 1u);
  }
}

// merged: degree norms (i<NN) + BN scale/shift (i<LL*HF)
__global__ void prep_kernel(const unsigned* __restrict__ cnt_out, const unsigned* __restrict__ cnt_in,
                            float* __restrict__ norm_src, float* __restrict__ norm_dst,
                            const float* __restrict__ bs, const float* __restrict__ gamma,
                            const float* __restrict__ beta, const float* __restrict__ rmean,
                            const float* __restrict__ rvar,
                            float* __restrict__ scale, float* __restrict__ shift) {
  int i = blockIdx.x * blockDim.x + threadIdx.x;
  if (i < NN) {
    unsigned co = cnt_out[i]; if (co < 1u) co = 1u;
    unsigned ci = cnt_in[i];  if (ci < 1u) ci = 1u;
    norm_src[i] = rsqrtf((float)co);
    norm_dst[i] = rsqrtf((float)ci);
  }
  if (i < LL * HF) {
    float s = gamma[i] * rsqrtf(rvar[i] + BN_EPS);
    scale[i] = s;
    shift[i] = (bs[i] - rmean[i]) * s + beta[i];
  }
}

// exclusive scan of cnt[0..NN) -> off[0..NN], single block of 1024
__global__ void scan_kernel(const unsigned* __restrict__ cnt, unsigned* __restrict__ off) {
  __shared__ unsigned wsum[16];
  int tid = threadIdx.x;
  int lane = tid & 63, wid = tid >> 6;
  unsigned base = 0;
  for (int c = 0; c < NN; c += 1024) {
    int i = c + tid;
    unsigned v = (i < NN) ? cnt[i] : 0u;
    unsigned x = v;
    #pragma unroll
    for (int d = 1; d < 64; d <<= 1) {
      unsigned y = __shfl_up(x, d, 64);
      if (lane >= d) x += y;
    }
    if (lane == 63) wsum[wid] = x;
    __syncthreads();
    if (wid == 0 && lane < 16) {
      unsigned s = wsum[lane];
      #pragma unroll
      for (int d = 1; d < 16; d <<= 1) {
        unsigned y = __shfl_up(s, d, 16);
        if (lane >= d) s += y;
      }
      wsum[lane] = s;
    }
    __syncthreads();
    unsigned wbase = wid ? wsum[wid - 1] : 0u;
    if (i < NN) off[i] = base + wbase + x - v;
    unsigned tot = wsum[15];
    __syncthreads();
    base += tot;
  }
  if (tid == 0) off[NN] = base;
}

__global__ void fill_kernel(const int* __restrict__ src, const int* __restrict__ dst,
                            const unsigned* __restrict__ off, unsigned* __restrict__ cursor,
                            int* __restrict__ edge_src) {
  int e = blockIdx.x * blockDim.x + threadIdx.x;
  if (e < NE) {
    int d = dst[e];
    unsigned p = atomicAdd(&cursor[d], 1u);
    edge_src[off[d] + p] = src[e];
  }
}

// ---------------- weight convert: W[k][n] fp32 -> Wt[n][k] fp16 ----------------
__global__ void convert_w(const float* __restrict__ W0, const float* __restrict__ Ws,
                          _Float16* __restrict__ Wt) {
  int l = blockIdx.z;
  const float* W = (l == 0) ? W0 : (Ws + (size_t)(l - 1) * HF * HF);
  __shared__ float t[32][33];
  int n0 = blockIdx.x * 32, k0 = blockIdx.y * 32;
  int tx = threadIdx.x & 31, ty4 = (threadIdx.x >> 5) * 4;
  #pragma unroll
  for (int j = 0; j < 4; ++j)
    t[ty4 + j][tx] = W[(size_t)(k0 + ty4 + j) * HF + n0 + tx];
  __syncthreads();
  size_t base = (size_t)l * HF * HF;
  #pragma unroll
  for (int j = 0; j < 4; ++j)
    Wt[base + (size_t)(n0 + ty4 + j) * HF + k0 + tx] = (_Float16)t[tx][ty4 + j];
}

// linW[k][c] fp32 -> Lt[c][k] fp16
__global__ void convert_lin(const float* __restrict__ linW, _Float16* __restrict__ Lt) {
  __shared__ float t[32][33];
  int n0 = blockIdx.x * 32, k0 = blockIdx.y * 32;
  int tx = threadIdx.x & 31, ty4 = (threadIdx.x >> 5) * 4;
  #pragma unroll
  for (int j = 0; j < 4; ++j)
    t[ty4 + j][tx] = linW[(size_t)(k0 + ty4 + j) * NC + n0 + tx];
  __syncthreads();
  #pragma unroll
  for (int j = 0; j < 4; ++j)
    Lt[(size_t)(n0 + ty4 + j) * KCAT + k0 + tx] = (_Float16)t[tx][ty4 + j];
}

// ---------------- x -> fp16 ----------------
__global__ void split_x(const float* __restrict__ x, _Float16* __restrict__ zh) {
  int i = blockIdx.x * blockDim.x + threadIdx.x;   // float4 index
  if (i >= NN * HF / 4) return;
  int base = i * 4;
  float4 v = *(const float4*)&x[base];
  f16x4 h;
  h.x = (_Float16)v.x;
  h.y = (_Float16)v.y;
  h.z = (_Float16)v.z;
  h.w = (_Float16)v.w;
  *(f16x4*)&zh[base] = h;
}

// ---------------- layer GEMM via MFMA: Mout = ns ⊙ (Z @ Wt^T) ----------------
// BM=64, BN=128, BK=64; 632 blocks (all co-resident at 3 blocks/CU -> no tail).
// XCD-bijective swizzle: 632 = 8*79; 4 consecutive wgids = 4 N-tiles of one M-tile
// on the same XCD -> A panel fetched once per XCD.
// 4 waves (2x2), wave tile 32x64 = 2x4 frags of 16x16x32_f16. ns applied at epilogue.
__launch_bounds__(256, 3)
__global__ void gemm_layer_f16(const _Float16* __restrict__ Z, int lda,
                               const _Float16* __restrict__ Wt,
                               const float* __restrict__ nsrc,
                               _Float16* __restrict__ Mout) {
  __shared__ _Float16 As[64][64];
  __shared__ _Float16 Bs[128][64];
  int bid = blockIdx.x;
  int wgid = (bid & 7) * 79 + (bid >> 3);   // bijective (632 % 8 == 0)
  int my = wgid >> 2, nx = wgid & 3;
  int m0 = my * 64;
  int n0 = nx * 128;
  int wid = threadIdx.x >> 6, lane = threadIdx.x & 63;
  int wr = wid >> 1, wc = wid & 1;
  int fr = lane & 15, kg = lane >> 4;
  int rr = lane >> 3;            // staging row within 8-row group
  int ck = (lane & 7) ^ rr;      // pre-swizzled source chunk

  f32x4 acc[2][4];
  #pragma unroll
  for (int m = 0; m < 2; ++m)
    #pragma unroll
    for (int n = 0; n < 4; ++n)
      acc[m][n] = (f32x4){0.f, 0.f, 0.f, 0.f};

  const _Float16* gA = Z  + (size_t)(m0 + wid * 16 + rr) * lda + ck * 8;
  const _Float16* gB = Wt + (size_t)(n0 + wid * 32 + rr) * HF + ck * 8;

  for (int k0 = 0; k0 < HF; k0 += 64) {
    __syncthreads();
    #pragma unroll
    for (int i = 0; i < 2; ++i)
      __builtin_amdgcn_global_load_lds(GLB(gA + (size_t)i * 8 * lda + k0),
                                       LDSP(&As[wid * 16 + i * 8][0]), 16, 0, 0);
    #pragma unroll
    for (int i = 0; i < 4; ++i)
      __builtin_amdgcn_global_load_lds(GLB(gB + (size_t)i * 8 * HF + k0),
                                       LDSP(&Bs[wid * 32 + i * 8][0]), 16, 0, 0);
    __syncthreads();
    #pragma unroll
    for (int kk = 0; kk < 2; ++kk) {
      f16x8 a[2], b[4];
      #pragma unroll
      for (int n = 0; n < 4; ++n) {
        int row = wc * 64 + n * 16 + fr;
        b[n] = *(const f16x8*)&Bs[row][((kk * 4 + kg) ^ (row & 7)) * 8];
      }
      #pragma unroll
      for (int m = 0; m < 2; ++m) {
        int row = wr * 32 + m * 16 + fr;
        a[m] = *(const f16x8*)&As[row][((kk * 4 + kg) ^ (row & 7)) * 8];
      }
      #pragma unroll
      for (int m = 0; m < 2; ++m)
        #pragma unroll
        for (int n = 0; n < 4; ++n)
          acc[m][n] = __builtin_amdgcn_mfma_f32_16x16x32_f16(a[m], b[n], acc[m][n], 0, 0, 0);
    }
  }
  // C/D layout: col (B-side) = fr, row (A-side) = kg*4 + j; scale rows by ns
  #pragma unroll
  for (int m = 0; m < 2; ++m) {
    #pragma unroll
    for (int j = 0; j < 4; ++j) {
      int row = m0 + wr * 32 + m * 16 + kg * 4 + j;
      if (row < NN) {
        float s = nsrc[row];
        #pragma unroll
        for (int n = 0; n < 4; ++n) {
          int col = n0 + wc * 64 + n * 16 + fr;
          Mout[(size_t)row * HF + col] = (_Float16)(acc[m][n][j] * s);
        }
      }
    }
  }
}

// ---------------- aggregation (pure gather+add) + norm_dst + BN + ReLU ----------------
// One 64-lane wave per node, f16x8 (16B) per lane = one instruction per 1KB source row.
// Mm rows are pre-scaled by ns[src] in the GEMM epilogue.
__launch_bounds__(256)
__global__ void agg_bn_kernel(const _Float16* __restrict__ Mm,
                              const int* __restrict__ edge_src,
                              const unsigned* __restrict__ row_off,
                              const float* __restrict__ norm_dst,
                              const float* __restrict__ bn_scale,  // + l*HF
                              const float* __restrict__ bn_shift,  // + l*HF
                              _Float16* __restrict__ hcat_col) {   // hcat + l*HF, stride KCAT
  int n = blockIdx.x * 4 + (threadIdx.x >> 6);
  if (n >= NN) return;
  int f = (threadIdx.x & 63) * 8;
  unsigned e0 = row_off[n], e1 = row_off[n + 1];
  float a0=0.f,a1=0.f,a2=0.f,a3=0.f,a4=0.f,a5=0.f,a6=0.f,a7=0.f;
  unsigned e = e0;
  for (; e + 4 <= e1; e += 4) {
    int s0 = edge_src[e], s1 = edge_src[e + 1], s2 = edge_src[e + 2], s3 = edge_src[e + 3];
    f16x8 v0 = *(const f16x8*)&Mm[(size_t)s0 * HF + f];
    f16x8 v1 = *(const f16x8*)&Mm[(size_t)s1 * HF + f];
    f16x8 v2 = *(const f16x8*)&Mm[(size_t)s2 * HF + f];
    f16x8 v3 = *(const f16x8*)&Mm[(size_t)s3 * HF + f];
    a0 += (float)v0[0]+(float)v1[0]+(float)v2[0]+(float)v3[0];
    a1 += (float)v0[1]+(float)v1[1]+(float)v2[1]+(float)v3[1];
    a2 += (float)v0[2]+(float)v1[2]+(float)v2[2]+(float)v3[2];
    a3 += (float)v0[3]+(float)v1[3]+(float)v2[3]+(float)v3[3];
    a4 += (float)v0[4]+(float)v1[4]+(float)v2[4]+(float)v3[4];
    a5 += (float)v0[5]+(float)v1[5]+(float)v2[5]+(float)v3[5];
    a6 += (float)v0[6]+(float)v1[6]+(float)v2[6]+(float)v3[6];
    a7 += (float)v0[7]+(float)v1[7]+(float)v2[7]+(float)v3[7];
  }
  for (; e < e1; ++e) {
    int s = edge_src[e];
    f16x8 v = *(const f16x8*)&Mm[(size_t)s * HF + f];
    a0 += (float)v[0]; a1 += (float)v[1]; a2 += (float)v[2]; a3 += (float)v[3];
    a4 += (float)v[4]; a5 += (float)v[5]; a6 += (float)v[6]; a7 += (float)v[7];
  }
  float nd = norm_dst[n];
  float4 s0 = *(const float4*)&bn_scale[f];
  float4 s1 = *(const float4*)&bn_scale[f + 4];
  float4 t0 = *(const float4*)&bn_shift[f];
  float4 t1 = *(const float4*)&bn_shift[f + 4];
  float y0 = fmaxf(fmaf(a0 * nd, s0.x, t0.x), 0.f);
  float y1 = fmaxf(fmaf(a1 * nd, s0.y, t0.y), 0.f);
  float y2 = fmaxf(fmaf(a2 * nd, s0.z, t0.z), 0.f);
  float y3 = fmaxf(fmaf(a3 * nd, s0.w, t0.w), 0.f);
  float y4 = fmaxf(fmaf(a4 * nd, s1.x, t1.x), 0.f);
  float y5 = fmaxf(fmaf(a5 * nd, s1.y, t1.y), 0.f);
  float y6 = fmaxf(fmaf(a6 * nd, s1.z, t1.z), 0.f);
  float y7 = fmaxf(fmaf(a7 * nd, s1.w, t1.w), 0.f);
  f16x8 hv;
  hv[0]=(_Float16)y0; hv[1]=(_Float16)y1; hv[2]=(_Float16)y2; hv[3]=(_Float16)y3;
  hv[4]=(_Float16)y4; hv[5]=(_Float16)y5; hv[6]=(_Float16)y6; hv[7]=(_Float16)y7;
  *(f16x8*)&hcat_col[(size_t)n * KCAT + f] = hv;
}

// ---------------- final GEMM via MFMA, split-K over 6 chunks, single-buffer ----------------
__launch_bounds__(256, 2)
__global__ void final_gemm_f16(const _Float16* __restrict__ Hc,
                               const _Float16* __restrict__ Lt,
                               float* __restrict__ part) {
  __shared__ _Float16 As[128][64];
  __shared__ _Float16 Bs[64][64];
  int m0 = blockIdx.x * 128;
  int sp = blockIdx.y;
  int kbase = sp * HF;
  int wid = threadIdx.x >> 6, lane = threadIdx.x & 63;
  int fr = lane & 15, kg = lane >> 4;
  int rr = lane >> 3;
  int ck = (lane & 7) ^ rr;

  f32x4 acc[2][4];
  #pragma unroll
  for (int m = 0; m < 2; ++m)
    #pragma unroll
    for (int n = 0; n < 4; ++n)
      acc[m][n] = (f32x4){0.f, 0.f, 0.f, 0.f};

  const _Float16* gA = Hc + (size_t)(m0 + wid * 32 + rr) * KCAT + kbase + ck * 8;
  const _Float16* gB = Lt + (size_t)(wid * 16 + rr) * KCAT + kbase + ck * 8;

  for (int k0 = 0; k0 < HF; k0 += 64) {
    __syncthreads();
    #pragma unroll
    for (int i = 0; i < 4; ++i)
      __builtin_amdgcn_global_load_lds(GLB(gA + (size_t)i * 8 * KCAT + k0),
                                       LDSP(&As[wid * 32 + i * 8][0]), 16, 0, 0);
    #pragma unroll
    for (int i = 0; i < 2; ++i)
      __builtin_amdgcn_global_load_lds(GLB(gB + (size_t)i * 8 * KCAT + k0),
                                       LDSP(&Bs[wid * 16 + i * 8][0]), 16, 0, 0);
    __syncthreads();
    #pragma unroll
    for (int kk = 0; kk < 2; ++kk) {
      f16x8 a[2], b[4];
      #pragma unroll
      for (int n = 0; n < 4; ++n) {
        int row = n * 16 + fr;
        b[n] = *(const f16x8*)&Bs[row][((kk * 4 + kg) ^ (row & 7)) * 8];
      }
      #pragma unroll
      for (int m = 0; m < 2; ++m) {
        int row = wid * 32 + m * 16 + fr;
        a[m] = *(const f16x8*)&As[row][((kk * 4 + kg) ^ (row & 7)) * 8];
      }
      #pragma unroll
      for (int m = 0; m < 2; ++m)
        #pragma unroll
        for (int n = 0; n < 4; ++n)
          acc[m][n] = __builtin_amdgcn_mfma_f32_16x16x32_f16(a[m], b[n], acc[m][n], 0, 0, 0);
    }
  }
  #pragma unroll
  for (int m = 0; m < 2; ++m) {
    #pragma unroll
    for (int j = 0; j < 4; ++j) {
      int row = m0 + wid * 32 + m * 16 + kg * 4 + j;
      if (row < NN) {
        #pragma unroll
        for (int n = 0; n < 4; ++n) {
          int col = n * 16 + fr;
          part[((size_t)sp * NN + row) * NC + col] = acc[m][n][j];
        }
      }
    }
  }
}

__launch_bounds__(256)
__global__ void final_reduce(const float* __restrict__ part,
                             const float* __restrict__ linb,
                             float* __restrict__ out) {
  int i = blockIdx.x * blockDim.x + threadIdx.x;   // float4 index
  if (i >= NN * NC / 4) return;
  int n  = i >> 4;
  int cq = i & 15;
  float4 s = *(const float4*)&linb[cq * 4];
  #pragma unroll
  for (int sp = 0; sp < LL; ++sp) {
    float4 v = *(const float4*)&part[((size_t)sp * NN + n) * NC + cq * 4];
    s.x += v.x; s.y += v.y; s.z += v.z; s.w += v.w;
  }
  *(float4*)&out[(size_t)n * NC + cq * 4] = s;
}

// ---------------- launch ----------------

extern "C" void kernel_launch(void* const* d_in, const int* in_sizes, int n_in,
                              void* d_out, int out_size, void* d_ws, size_t ws_size,
                              hipStream_t stream) {
  const float* x     = (const float*)d_in[0];
  const float* W0    = (const float*)d_in[1];
  const float* Ws    = (const float*)d_in[2];
  const float* bs    = (const float*)d_in[3];
  const float* gamma = (const float*)d_in[4];
  const float* beta  = (const float*)d_in[5];
  const float* rmean = (const float*)d_in[6];
  const float* rvar  = (const float*)d_in[7];
  const float* linW  = (const float*)d_in[8];
  const float* linb  = (const float*)d_in[9];
  const int*   src   = (const int*)d_in[10];
  const int*   dst   = (const int*)d_in[11];
  float* out = (float*)d_out;

  char* w = (char*)d_ws;
  size_t o = 0;
  auto carve = [&](size_t bytes) -> void* {
    o = (o + 255) & ~(size_t)255;
    void* p = w + o;
    o += bytes;
    return p;
  };
  _Float16*  m_buf = (_Float16*)carve((size_t)NNPAD * HF * 2);
  _Float16*  hcat  = (_Float16*)carve((size_t)NNPAD * KCAT * 2);
  _Float16*  zh    = (_Float16*)carve((size_t)NNPAD * HF * 2);   // layer-0 input only
  _Float16*  wt    = (_Float16*)carve((size_t)LL * HF * HF * 2);
  _Float16*  lt    = (_Float16*)carve((size_t)NC * KCAT * 2);
  float*     part  = (float*)carve((size_t)LL * NN * NC * 4);
  float*     bnsc  = (float*)carve((size_t)LL * HF * 4);
  float*     bnsh  = (float*)carve((size_t)LL * HF * 4);
  float*     nsrc  = (float*)carve((size_t)NN * 4);
  float*     ndst  = (float*)carve((size_t)NN * 4);
  unsigned*  cnts  = (unsigned*)carve((size_t)3 * NN * 4);
  unsigned*  roff  = (unsigned*)carve((size_t)(NN + 1) * 4);
  int*       esrc  = (int*)carve((size_t)NE * 4);

  unsigned* cnt_out = cnts;
  unsigned* cnt_in  = cnts + NN;
  unsigned* cursor  = cnts + 2 * NN;

  zero_u32_kernel<<<(3 * NN + 255) / 256, 256, 0, stream>>>(cnts, 3 * NN);
  deg_kernel<<<(NE + 255) / 256, 256, 0, stream>>>(src, dst, cnt_out, cnt_in);
  prep_kernel<<<(NN + 255) / 256, 256, 0, stream>>>(cnt_out, cnt_in, nsrc, ndst,
                                                    bs, gamma, beta, rmean, rvar, bnsc, bnsh);
  scan_kernel<<<1, 1024, 0, stream>>>(cnt_in, roff);
  fill_kernel<<<(NE + 255) / 256, 256, 0, stream>>>(src, dst, roff, cursor, esrc);
  convert_w<<<dim3(16, 16, 6), 256, 0, stream>>>(W0, Ws, wt);
  convert_lin<<<dim3(2, 96), 256, 0, stream>>>(linW, lt);
  split_x<<<(NN * HF / 4 + 255) / 256, 256, 0, stream>>>(x, zh);

  for (int l = 0; l < LL; ++l) {
    const _Float16* A   = (l == 0) ? zh : (hcat + (size_t)(l - 1) * HF);
    int             lda = (l == 0) ? HF : KCAT;
    gemm_layer_f16<<<632, 256, 0, stream>>>(A, lda, wt + (size_t)l * HF * HF, nsrc, m_buf);
    agg_bn_kernel<<<(NN + 3) / 4, 256, 0, stream>>>(m_buf, esrc, roff, ndst,
                                                    bnsc + l * HF, bnsh + l * HF,
                                                    hcat + (size_t)l * HF);
  }
  final_gemm_f16<<<dim3(NNPAD / 128, LL), 256, 0, stream>>>(hcat, lt, part);
  final_reduce<<<(NN * NC / 4 + 255) / 256, 256, 0, stream>>>(part, linb, out);
}

// Round 9
// 276.881 us; speedup vs baseline: 1.0418x; 1.0418x over previous
//
#include <hip/hip_runtime.h>

#define NN 10000      // nodes
#define NNPAD 10112   // padded: 79*128
#define NE 160000     // edges
#define HF 512        // hidden/in features
#define LL 6          // layers
#define NC 64         // classes
#define KCAT (LL*HF)  // 3072
#define BN_EPS 1e-5f
#define FSPLIT 3      // final GEMM split-K chunks (K=1024 each)

typedef _Float16 f16x8 __attribute__((ext_vector_type(8)));
typedef _Float16 f16x4 __attribute__((ext_vector_type(4)));
typedef float f32x4 __attribute__((ext_vector_type(4)));

#define GLB(p) ((const __attribute__((address_space(1))) void*)(p))
#define LDSP(p) ((__attribute__((address_space(3))) void*)(p))

// ---------------- setup kernels ----------------

__global__ void zero_u32_kernel(unsigned* __restrict__ p, int n) {
  int i = blockIdx.x * blockDim.x + threadIdx.x;
  if (i < n) p[i] = 0u;
}

__global__ void deg_kernel(const int* __restrict__ src, const int* __restrict__ dst,
                           unsigned* __restrict__ cnt_out, unsigned* __restrict__ cnt_in) {
  int e = blockIdx.x * blockDim.x + threadIdx.x;
  if (e < NE) {
    atomicAdd(&cnt_out[src[e]], 1u);
    atomicAdd(&cnt_in[dst[e]], 1u);
  }
}

// merged: degree norms (i<NN) + BN scale/shift (i<LL*HF)
__global__ void prep_kernel(const unsigned* __restrict__ cnt_out, const unsigned* __restrict__ cnt_in,
                            float* __restrict__ norm_src, float* __restrict__ norm_dst,
                            const float* __restrict__ bs, const float* __restrict__ gamma,
                            const float* __restrict__ beta, const float* __restrict__ rmean,
                            const float* __restrict__ rvar,
                            float* __restrict__ scale, float* __restrict__ shift) {
  int i = blockIdx.x * blockDim.x + threadIdx.x;
  if (i < NN) {
    unsigned co = cnt_out[i]; if (co < 1u) co = 1u;
    unsigned ci = cnt_in[i];  if (ci < 1u) ci = 1u;
    norm_src[i] = rsqrtf((float)co);
    norm_dst[i] = rsqrtf((float)ci);
  }
  if (i < LL * HF) {
    float s = gamma[i] * rsqrtf(rvar[i] + BN_EPS);
    scale[i] = s;
    shift[i] = (bs[i] - rmean[i]) * s + beta[i];
  }
}

// exclusive scan of cnt[0..NN) -> off[0..NN], single block of 1024
__global__ void scan_kernel(const unsigned* __restrict__ cnt, unsigned* __restrict__ off) {
  __shared__ unsigned wsum[16];
  int tid = threadIdx.x;
  int lane = tid & 63, wid = tid >> 6;
  unsigned base = 0;
  for (int c = 0; c < NN; c += 1024) {
    int i = c + tid;
    unsigned v = (i < NN) ? cnt[i] : 0u;
    unsigned x = v;
    #pragma unroll
    for (int d = 1; d < 64; d <<= 1) {
      unsigned y = __shfl_up(x, d, 64);
      if (lane >= d) x += y;
    }
    if (lane == 63) wsum[wid] = x;
    __syncthreads();
    if (wid == 0 && lane < 16) {
      unsigned s = wsum[lane];
      #pragma unroll
      for (int d = 1; d < 16; d <<= 1) {
        unsigned y = __shfl_up(s, d, 16);
        if (lane >= d) s += y;
      }
      wsum[lane] = s;
    }
    __syncthreads();
    unsigned wbase = wid ? wsum[wid - 1] : 0u;
    if (i < NN) off[i] = base + wbase + x - v;
    unsigned tot = wsum[15];
    __syncthreads();
    base += tot;
  }
  if (tid == 0) off[NN] = base;
}

__global__ void fill_kernel(const int* __restrict__ src, const int* __restrict__ dst,
                            const unsigned* __restrict__ off, unsigned* __restrict__ cursor,
                            int* __restrict__ edge_src) {
  int e = blockIdx.x * blockDim.x + threadIdx.x;
  if (e < NE) {
    int d = dst[e];
    unsigned p = atomicAdd(&cursor[d], 1u);
    edge_src[off[d] + p] = src[e];
  }
}

// ---------------- weight convert: W[k][n] fp32 -> Wt[n][k] fp16 ----------------
__global__ void convert_w(const float* __restrict__ W0, const float* __restrict__ Ws,
                          _Float16* __restrict__ Wt) {
  int l = blockIdx.z;
  const float* W = (l == 0) ? W0 : (Ws + (size_t)(l - 1) * HF * HF);
  __shared__ float t[32][33];
  int n0 = blockIdx.x * 32, k0 = blockIdx.y * 32;
  int tx = threadIdx.x & 31, ty4 = (threadIdx.x >> 5) * 4;
  #pragma unroll
  for (int j = 0; j < 4; ++j)
    t[ty4 + j][tx] = W[(size_t)(k0 + ty4 + j) * HF + n0 + tx];
  __syncthreads();
  size_t base = (size_t)l * HF * HF;
  #pragma unroll
  for (int j = 0; j < 4; ++j)
    Wt[base + (size_t)(n0 + ty4 + j) * HF + k0 + tx] = (_Float16)t[tx][ty4 + j];
}

// linW[k][c] fp32 -> Lt[c][k] fp16
__global__ void convert_lin(const float* __restrict__ linW, _Float16* __restrict__ Lt) {
  __shared__ float t[32][33];
  int n0 = blockIdx.x * 32, k0 = blockIdx.y * 32;
  int tx = threadIdx.x & 31, ty4 = (threadIdx.x >> 5) * 4;
  #pragma unroll
  for (int j = 0; j < 4; ++j)
    t[ty4 + j][tx] = linW[(size_t)(k0 + ty4 + j) * NC + n0 + tx];
  __syncthreads();
  #pragma unroll
  for (int j = 0; j < 4; ++j)
    Lt[(size_t)(n0 + ty4 + j) * KCAT + k0 + tx] = (_Float16)t[tx][ty4 + j];
}

// ---------------- x -> fp16 ----------------
__global__ void split_x(const float* __restrict__ x, _Float16* __restrict__ zh) {
  int i = blockIdx.x * blockDim.x + threadIdx.x;   // float4 index
  if (i >= NN * HF / 4) return;
  int base = i * 4;
  float4 v = *(const float4*)&x[base];
  f16x4 h;
  h.x = (_Float16)v.x;
  h.y = (_Float16)v.y;
  h.z = (_Float16)v.z;
  h.w = (_Float16)v.w;
  *(f16x4*)&zh[base] = h;
}

// ---------------- layer GEMM via MFMA: Mout = ns ⊙ (Z @ Wt^T) (r7 tiling) ----------------
// 128x128 tile, BK=64, 4 waves (2x2), wave tile 64x64 = 4x4 frags of 16x16x32_f16.
__launch_bounds__(256, 2)
__global__ void gemm_layer_f16(const _Float16* __restrict__ Z, int lda,
                               const _Float16* __restrict__ Wt,
                               const float* __restrict__ nsrc,
                               _Float16* __restrict__ Mout) {
  __shared__ _Float16 As[128][64];
  __shared__ _Float16 Bs[128][64];
  int m0 = blockIdx.y * 128;
  int n0 = blockIdx.x * 128;
  int wid = threadIdx.x >> 6, lane = threadIdx.x & 63;
  int wr = wid >> 1, wc = wid & 1;
  int fr = lane & 15, kg = lane >> 4;
  int rr = lane >> 3;            // staging row within 8-row group
  int ck = (lane & 7) ^ rr;      // pre-swizzled source chunk

  f32x4 acc[4][4];
  #pragma unroll
  for (int m = 0; m < 4; ++m)
    #pragma unroll
    for (int n = 0; n < 4; ++n)
      acc[m][n] = (f32x4){0.f, 0.f, 0.f, 0.f};

  const _Float16* gA = Z  + (size_t)(m0 + wid * 32 + rr) * lda + ck * 8;
  const _Float16* gB = Wt + (size_t)(n0 + wid * 32 + rr) * HF + ck * 8;

  for (int k0 = 0; k0 < HF; k0 += 64) {
    __syncthreads();
    #pragma unroll
    for (int i = 0; i < 4; ++i) {
      __builtin_amdgcn_global_load_lds(GLB(gA + (size_t)i * 8 * lda + k0),
                                       LDSP(&As[wid * 32 + i * 8][0]), 16, 0, 0);
      __builtin_amdgcn_global_load_lds(GLB(gB + (size_t)i * 8 * HF + k0),
                                       LDSP(&Bs[wid * 32 + i * 8][0]), 16, 0, 0);
    }
    __syncthreads();
    #pragma unroll
    for (int kk = 0; kk < 2; ++kk) {
      f16x8 a[4], b[4];
      #pragma unroll
      for (int n = 0; n < 4; ++n) {
        int row = wc * 64 + n * 16 + fr;
        b[n] = *(const f16x8*)&Bs[row][((kk * 4 + kg) ^ (row & 7)) * 8];
      }
      #pragma unroll
      for (int m = 0; m < 4; ++m) {
        int row = wr * 64 + m * 16 + fr;
        a[m] = *(const f16x8*)&As[row][((kk * 4 + kg) ^ (row & 7)) * 8];
      }
      #pragma unroll
      for (int m = 0; m < 4; ++m)
        #pragma unroll
        for (int n = 0; n < 4; ++n)
          acc[m][n] = __builtin_amdgcn_mfma_f32_16x16x32_f16(a[m], b[n], acc[m][n], 0, 0, 0);
    }
  }
  // C/D layout: col = lane&15, row = (lane>>4)*4 + j; scale rows by ns at epilogue
  #pragma unroll
  for (int m = 0; m < 4; ++m) {
    #pragma unroll
    for (int j = 0; j < 4; ++j) {
      int row = m0 + wr * 64 + m * 16 + kg * 4 + j;
      if (row < NN) {
        float s = nsrc[row];
        #pragma unroll
        for (int n = 0; n < 4; ++n) {
          int col = n0 + wc * 64 + n * 16 + fr;
          Mout[(size_t)row * HF + col] = (_Float16)(acc[m][n][j] * s);
        }
      }
    }
  }
}

// ---------------- aggregation, feature-chunked + XCD-pinned ----------------
// 4 chunks of 128 cols; slice = NNPAD x 256B = 2.6 MB < 4 MB per-XCD L2.
// chunk = (blockIdx&7)>>1 -> blockIdx%8 round-robins XCDs, so each XCD touches ONE slice.
// 16 lanes per node (f16x8 = 16B each), 4 nodes/wave, 16 nodes/block.
// Mm rows pre-scaled by ns[src] in GEMM epilogue -> pure gather+add.
__launch_bounds__(256)
__global__ void agg_bn_kernel(const _Float16* __restrict__ Mm,
                              const int* __restrict__ edge_src,
                              const unsigned* __restrict__ row_off,
                              const float* __restrict__ norm_dst,
                              const float* __restrict__ bn_scale,  // + l*HF
                              const float* __restrict__ bn_shift,  // + l*HF
                              _Float16* __restrict__ hcat_col) {   // hcat + l*HF, stride KCAT
  int s     = blockIdx.x & 7;
  int chunk = s >> 1;                       // 0..3
  int grp   = blockIdx.x >> 3;              // 0..312
  int wave  = threadIdx.x >> 6;
  int sub   = (threadIdx.x >> 4) & 3;
  int n = grp * 32 + (s & 1) * 16 + wave * 4 + sub;
  if (n >= NN) return;
  int f = chunk * 128 + (threadIdx.x & 15) * 8;
  unsigned e0 = row_off[n], e1 = row_off[n + 1];
  float a0=0.f,a1=0.f,a2=0.f,a3=0.f,a4=0.f,a5=0.f,a6=0.f,a7=0.f;
  unsigned e = e0;
  for (; e + 4 <= e1; e += 4) {
    int s0 = edge_src[e], s1 = edge_src[e + 1], s2 = edge_src[e + 2], s3 = edge_src[e + 3];
    f16x8 v0 = *(const f16x8*)&Mm[(size_t)s0 * HF + f];
    f16x8 v1 = *(const f16x8*)&Mm[(size_t)s1 * HF + f];
    f16x8 v2 = *(const f16x8*)&Mm[(size_t)s2 * HF + f];
    f16x8 v3 = *(const f16x8*)&Mm[(size_t)s3 * HF + f];
    a0 += (float)v0[0]+(float)v1[0]+(float)v2[0]+(float)v3[0];
    a1 += (float)v0[1]+(float)v1[1]+(float)v2[1]+(float)v3[1];
    a2 += (float)v0[2]+(float)v1[2]+(float)v2[2]+(float)v3[2];
    a3 += (float)v0[3]+(float)v1[3]+(float)v2[3]+(float)v3[3];
    a4 += (float)v0[4]+(float)v1[4]+(float)v2[4]+(float)v3[4];
    a5 += (float)v0[5]+(float)v1[5]+(float)v2[5]+(float)v3[5];
    a6 += (float)v0[6]+(float)v1[6]+(float)v2[6]+(float)v3[6];
    a7 += (float)v0[7]+(float)v1[7]+(float)v2[7]+(float)v3[7];
  }
  for (; e < e1; ++e) {
    int sx = edge_src[e];
    f16x8 v = *(const f16x8*)&Mm[(size_t)sx * HF + f];
    a0 += (float)v[0]; a1 += (float)v[1]; a2 += (float)v[2]; a3 += (float)v[3];
    a4 += (float)v[4]; a5 += (float)v[5]; a6 += (float)v[6]; a7 += (float)v[7];
  }
  float nd = norm_dst[n];
  float4 s0 = *(const float4*)&bn_scale[f];
  float4 s1 = *(const float4*)&bn_scale[f + 4];
  float4 t0 = *(const float4*)&bn_shift[f];
  float4 t1 = *(const float4*)&bn_shift[f + 4];
  float y0 = fmaxf(fmaf(a0 * nd, s0.x, t0.x), 0.f);
  float y1 = fmaxf(fmaf(a1 * nd, s0.y, t0.y), 0.f);
  float y2 = fmaxf(fmaf(a2 * nd, s0.z, t0.z), 0.f);
  float y3 = fmaxf(fmaf(a3 * nd, s0.w, t0.w), 0.f);
  float y4 = fmaxf(fmaf(a4 * nd, s1.x, t1.x), 0.f);
  float y5 = fmaxf(fmaf(a5 * nd, s1.y, t1.y), 0.f);
  float y6 = fmaxf(fmaf(a6 * nd, s1.z, t1.z), 0.f);
  float y7 = fmaxf(fmaf(a7 * nd, s1.w, t1.w), 0.f);
  f16x8 hv;
  hv[0]=(_Float16)y0; hv[1]=(_Float16)y1; hv[2]=(_Float16)y2; hv[3]=(_Float16)y3;
  hv[4]=(_Float16)y4; hv[5]=(_Float16)y5; hv[6]=(_Float16)y6; hv[7]=(_Float16)y7;
  *(f16x8*)&hcat_col[(size_t)n * KCAT + f] = hv;
}

// ---------------- final GEMM via MFMA, split-K over 3 chunks (K=1024 each) ----------------
__launch_bounds__(256, 2)
__global__ void final_gemm_f16(const _Float16* __restrict__ Hc,
                               const _Float16* __restrict__ Lt,
                               float* __restrict__ part) {
  __shared__ _Float16 As[128][64];
  __shared__ _Float16 Bs[64][64];
  int m0 = blockIdx.x * 128;
  int sp = blockIdx.y;
  int kbase = sp * (KCAT / FSPLIT);
  int wid = threadIdx.x >> 6, lane = threadIdx.x & 63;
  int fr = lane & 15, kg = lane >> 4;
  int rr = lane >> 3;
  int ck = (lane & 7) ^ rr;

  f32x4 acc[2][4];
  #pragma unroll
  for (int m = 0; m < 2; ++m)
    #pragma unroll
    for (int n = 0; n < 4; ++n)
      acc[m][n] = (f32x4){0.f, 0.f, 0.f, 0.f};

  const _Float16* gA = Hc + (size_t)(m0 + wid * 32 + rr) * KCAT + kbase + ck * 8;
  const _Float16* gB = Lt + (size_t)(wid * 16 + rr) * KCAT + kbase + ck * 8;

  for (int k0 = 0; k0 < KCAT / FSPLIT; k0 += 64) {
    __syncthreads();
    #pragma unroll
    for (int i = 0; i < 4; ++i)
      __builtin_amdgcn_global_load_lds(GLB(gA + (size_t)i * 8 * KCAT + k0),
                                       LDSP(&As[wid * 32 + i * 8][0]), 16, 0, 0);
    #pragma unroll
    for (int i = 0; i < 2; ++i)
      __builtin_amdgcn_global_load_lds(GLB(gB + (size_t)i * 8 * KCAT + k0),
                                       LDSP(&Bs[wid * 16 + i * 8][0]), 16, 0, 0);
    __syncthreads();
    #pragma unroll
    for (int kk = 0; kk < 2; ++kk) {
      f16x8 a[2], b[4];
      #pragma unroll
      for (int n = 0; n < 4; ++n) {
        int row = n * 16 + fr;
        b[n] = *(const f16x8*)&Bs[row][((kk * 4 + kg) ^ (row & 7)) * 8];
      }
      #pragma unroll
      for (int m = 0; m < 2; ++m) {
        int row = wid * 32 + m * 16 + fr;
        a[m] = *(const f16x8*)&As[row][((kk * 4 + kg) ^ (row & 7)) * 8];
      }
      #pragma unroll
      for (int m = 0; m < 2; ++m)
        #pragma unroll
        for (int n = 0; n < 4; ++n)
          acc[m][n] = __builtin_amdgcn_mfma_f32_16x16x32_f16(a[m], b[n], acc[m][n], 0, 0, 0);
    }
  }
  #pragma unroll
  for (int m = 0; m < 2; ++m) {
    #pragma unroll
    for (int j = 0; j < 4; ++j) {
      int row = m0 + wid * 32 + m * 16 + kg * 4 + j;
      if (row < NN) {
        #pragma unroll
        for (int n = 0; n < 4; ++n) {
          int col = n * 16 + fr;
          part[((size_t)sp * NN + row) * NC + col] = acc[m][n][j];
        }
      }
    }
  }
}

__launch_bounds__(256)
__global__ void final_reduce(const float* __restrict__ part,
                             const float* __restrict__ linb,
                             float* __restrict__ out) {
  int i = blockIdx.x * blockDim.x + threadIdx.x;   // float4 index
  if (i >= NN * NC / 4) return;
  int n  = i >> 4;
  int cq = i & 15;
  float4 s = *(const float4*)&linb[cq * 4];
  #pragma unroll
  for (int sp = 0; sp < FSPLIT; ++sp) {
    float4 v = *(const float4*)&part[((size_t)sp * NN + n) * NC + cq * 4];
    s.x += v.x; s.y += v.y; s.z += v.z; s.w += v.w;
  }
  *(float4*)&out[(size_t)n * NC + cq * 4] = s;
}

// ---------------- launch ----------------

extern "C" void kernel_launch(void* const* d_in, const int* in_sizes, int n_in,
                              void* d_out, int out_size, void* d_ws, size_t ws_size,
                              hipStream_t stream) {
  const float* x     = (const float*)d_in[0];
  const float* W0    = (const float*)d_in[1];
  const float* Ws    = (const float*)d_in[2];
  const float* bs    = (const float*)d_in[3];
  const float* gamma = (const float*)d_in[4];
  const float* beta  = (const float*)d_in[5];
  const float* rmean = (const float*)d_in[6];
  const float* rvar  = (const float*)d_in[7];
  const float* linW  = (const float*)d_in[8];
  const float* linb  = (const float*)d_in[9];
  const int*   src   = (const int*)d_in[10];
  const int*   dst   = (const int*)d_in[11];
  float* out = (float*)d_out;

  char* w = (char*)d_ws;
  size_t o = 0;
  auto carve = [&](size_t bytes) -> void* {
    o = (o + 255) & ~(size_t)255;
    void* p = w + o;
    o += bytes;
    return p;
  };
  _Float16*  m_buf = (_Float16*)carve((size_t)NNPAD * HF * 2);
  _Float16*  hcat  = (_Float16*)carve((size_t)NNPAD * KCAT * 2);
  _Float16*  zh    = (_Float16*)carve((size_t)NNPAD * HF * 2);   // layer-0 input only
  _Float16*  wt    = (_Float16*)carve((size_t)LL * HF * HF * 2);
  _Float16*  lt    = (_Float16*)carve((size_t)NC * KCAT * 2);
  float*     part  = (float*)carve((size_t)FSPLIT * NN * NC * 4);
  float*     bnsc  = (float*)carve((size_t)LL * HF * 4);
  float*     bnsh  = (float*)carve((size_t)LL * HF * 4);
  float*     nsrc  = (float*)carve((size_t)NN * 4);
  float*     ndst  = (float*)carve((size_t)NN * 4);
  unsigned*  cnts  = (unsigned*)carve((size_t)3 * NN * 4);
  unsigned*  roff  = (unsigned*)carve((size_t)(NN + 1) * 4);
  int*       esrc  = (int*)carve((size_t)NE * 4);

  unsigned* cnt_out = cnts;
  unsigned* cnt_in  = cnts + NN;
  unsigned* cursor  = cnts + 2 * NN;

  zero_u32_kernel<<<(3 * NN + 255) / 256, 256, 0, stream>>>(cnts, 3 * NN);
  deg_kernel<<<(NE + 255) / 256, 256, 0, stream>>>(src, dst, cnt_out, cnt_in);
  prep_kernel<<<(NN + 255) / 256, 256, 0, stream>>>(cnt_out, cnt_in, nsrc, ndst,
                                                    bs, gamma, beta, rmean, rvar, bnsc, bnsh);
  scan_kernel<<<1, 1024, 0, stream>>>(cnt_in, roff);
  fill_kernel<<<(NE + 255) / 256, 256, 0, stream>>>(src, dst, roff, cursor, esrc);
  convert_w<<<dim3(16, 16, 6), 256, 0, stream>>>(W0, Ws, wt);
  convert_lin<<<dim3(2, 96), 256, 0, stream>>>(linW, lt);
  split_x<<<(NN * HF / 4 + 255) / 256, 256, 0, stream>>>(x, zh);

  int agg_blocks = ((NN + 31) / 32) * 8;   // 313 * 8 = 2504
  for (int l = 0; l < LL; ++l) {
    const _Float16* A   = (l == 0) ? zh : (hcat + (size_t)(l - 1) * HF);
    int             lda = (l == 0) ? HF : KCAT;
    gemm_layer_f16<<<dim3(HF / 128, NNPAD / 128), 256, 0, stream>>>(
        A, lda, wt + (size_t)l * HF * HF, nsrc, m_buf);
    agg_bn_kernel<<<agg_blocks, 256, 0, stream>>>(m_buf, esrc, roff, ndst,
                                                  bnsc + l * HF, bnsh + l * HF,
                                                  hcat + (size_t)l * HF);
  }
  final_gemm_f16<<<dim3(NNPAD / 128, FSPLIT), 256, 0, stream>>>(hcat, lt, part);
  final_reduce<<<(NN * NC / 4 + 255) / 256, 256, 0, stream>>>(part, linb, out);
}